// Round 4
// baseline (69.540 us; speedup 1.0000x reference)
//
#include <hip/hip_runtime.h>
#include <hip/hip_bf16.h>

typedef __attribute__((ext_vector_type(8))) short bf16x8;
typedef __attribute__((ext_vector_type(4))) float f32x4;

__device__ __forceinline__ short f2bf(float x) {
    __hip_bfloat16 t = __float2bfloat16(x);
    return __builtin_bit_cast(short, t);
}

// B=16, N=4096, K=16, hidden=64, dim=64
// 65,536 groups of 16 rows (group = one point's 16 neighbors).
// grid: 512 blocks x 256 threads = 2048 waves; each wave owns the ADJACENT
// pair (2*wid, 2*wid+1) + t*4096, 16 iterations.
//
// R4 changes (one mechanism: outstanding-store capacity):
//  - plain stores instead of nontemporal (ACK at L2, writeback decoupled)
//  - 2 groups/iteration -> 2KB store cluster per wave-iter, 8KB contiguous
//  - loads for t+1/t+2 issued before stores of t (in-order vmcnt never
//    forces a store drain)

__global__ __launch_bounds__(256, 2) void ppe_kernel(
    const float* __restrict__ xyz,   // [16,4096,3]
    const float* __restrict__ dist,  // [16,4096,16]
    const float* __restrict__ W1,    // [10,64]
    const float* __restrict__ b1,    // [64]
    const float* __restrict__ W2,    // [64,64]
    const float* __restrict__ b2,    // [64]
    const int*   __restrict__ idx,   // [16,4096,16] (int32)
    float* __restrict__ out)         // [16,4096,16,64]
{
    __shared__ float sbuf[4][2][1024];  // 8 KB per wave

    const int lane = threadIdx.x & 63;
    const int warp = threadIdx.x >> 6;
    const int wid  = (blockIdx.x * blockDim.x + threadIdx.x) >> 6; // 0..2047
    const int u    = lane >> 4;   // 0..3
    const int p    = lane & 15;   // 0..15

    // ---- hoist weights into registers ----
    // wa[c] = W1[c]+W1[6+c] (center), wb[c] = W1[3+c]-W1[6+c] (neighbor), wd = W1[9].
    float wa[3][16], wb[3][16], wd[16], bb1[16];
#pragma unroll
    for (int t = 0; t < 2; ++t) {
        const int hd0 = t * 32 + u * 8;
#pragma unroll
        for (int j = 0; j < 8; ++j) {
            const int hd = hd0 + j;
            const int li = t * 8 + j;
#pragma unroll
            for (int c = 0; c < 3; ++c) {
                float wc_ = W1[c * 64 + hd];
                float wn_ = W1[(3 + c) * 64 + hd];
                float wr_ = W1[(6 + c) * 64 + hd];
                wa[c][li] = wc_ + wr_;
                wb[c][li] = wn_ - wr_;
            }
            wd[li]  = W1[9 * 64 + hd];
            bb1[li] = b1[hd];
        }
    }

    bf16x8 w2f[2][4];
#pragma unroll
    for (int kt = 0; kt < 2; ++kt)
#pragma unroll
        for (int ct = 0; ct < 4; ++ct)
#pragma unroll
            for (int j = 0; j < 8; ++j)
                w2f[kt][ct][j] = f2bf(W2[(kt * 32 + u * 8 + j) * 64 + ct * 16 + p]);

    float b2r[4];
#pragma unroll
    for (int ct = 0; ct < 4; ++ct) b2r[ct] = b2[ct * 16 + p];

    const int NIT = 16, STRIDE = 4096;
    const int gbase = 2 * wid;               // adjacent pair per wave

    // ---- pipeline state (per group slot s=0,1) ----
    float cC[2][3], nC[2][3], dC[2];         // operands for iteration t
    int   nbN[2];  float dN[2];              // idx/dist for iteration t+1

    // prologue: stageA(0) + stageB(0) + stageA(1)
#pragma unroll
    for (int s = 0; s < 2; ++s) {
        const int g  = gbase + s;
        const int r0 = g * 16 + p;
        int   nb0 = idx[r0];
        dC[s]     = dist[r0];
        const float* cp = xyz + (size_t)g * 3;
        cC[s][0] = cp[0]; cC[s][1] = cp[1]; cC[s][2] = cp[2];
        const float* np = xyz + ((size_t)(g & ~4095) + nb0) * 3;
        nC[s][0] = np[0]; nC[s][1] = np[1]; nC[s][2] = np[2];
        const int r1 = (g + STRIDE) * 16 + p;
        nbN[s] = idx[r1];
        dN[s]  = dist[r1];
    }

    for (int t = 0; t < NIT; ++t) {
        const int gc = gbase + t * STRIDE;
        const int gB = (t < NIT - 1) ? gc + STRIDE     : gc;  // t+1 (clamped dummy)
        const int gA = (t < NIT - 2) ? gc + 2 * STRIDE : gc;  // t+2 (clamped dummy)

        // ---- 1. issue stageB(t+1): center + neighbor xyz (addr from resident nbN) ----
        float cL[2][3], nL[2][3];
#pragma unroll
        for (int s = 0; s < 2; ++s) {
            const int g = gB + s;
            const float* cp = xyz + (size_t)g * 3;
            cL[s][0] = cp[0]; cL[s][1] = cp[1]; cL[s][2] = cp[2];
            const float* np = xyz + ((size_t)(g & ~4095) + nbN[s]) * 3;
            nL[s][0] = np[0]; nL[s][1] = np[1]; nL[s][2] = np[2];
        }

        // ---- 2. issue stageA(t+2): idx + dist ----
        int nbL[2]; float dL[2];
#pragma unroll
        for (int s = 0; s < 2; ++s) {
            const int rA = (gA + s) * 16 + p;
            nbL[s] = idx[rA];
            dL[s]  = dist[rA];
        }

        // ---- 3. compute both groups, park in LDS ----
#pragma unroll
        for (int s = 0; s < 2; ++s) {
            float h[16];
#pragma unroll
            for (int i = 0; i < 16; ++i) {
                float v = bb1[i];
                v = fmaf(cC[s][0], wa[0][i], v);
                v = fmaf(cC[s][1], wa[1][i], v);
                v = fmaf(cC[s][2], wa[2][i], v);
                v = fmaf(nC[s][0], wb[0][i], v);
                v = fmaf(nC[s][1], wb[1][i], v);
                v = fmaf(nC[s][2], wb[2][i], v);
                v = fmaf(dC[s],    wd[i],    v);
                h[i] = fmaxf(v, 0.0f);
            }

            bf16x8 a0, a1;
#pragma unroll
            for (int j = 0; j < 8; ++j) { a0[j] = f2bf(h[j]); a1[j] = f2bf(h[8 + j]); }

            f32x4 acc[4];
#pragma unroll
            for (int ct = 0; ct < 4; ++ct) {
                acc[ct] = (f32x4){0.f, 0.f, 0.f, 0.f};
                acc[ct] = __builtin_amdgcn_mfma_f32_16x16x32_bf16(a0, w2f[0][ct], acc[ct], 0, 0, 0);
                acc[ct] = __builtin_amdgcn_mfma_f32_16x16x32_bf16(a1, w2f[1][ct], acc[ct], 0, 0, 0);
            }

            // fragment -> LDS (swizzled: 2-way banks = free)
            float* const ws = &sbuf[warp][s][0];
#pragma unroll
            for (int ct = 0; ct < 4; ++ct) {
                const int cswz = (ct * 16 + p) ^ (u << 2) ^ ((u & 1) << 4);
                const int base = (u * 4) * 64 + cswz;
                ws[base      ] = acc[ct][0] + b2r[ct];
                ws[base +  64] = acc[ct][1] + b2r[ct];
                ws[base + 128] = acc[ct][2] + b2r[ct];
                ws[base + 192] = acc[ct][3] + b2r[ct];
            }
        }

        // ---- 4. store cluster: 8 x 1KB contiguous dwordx4 (8 KB per wave) ----
#pragma unroll
        for (int s = 0; s < 2; ++s) {
            float* const obase = out + (size_t)(gc + s) * 1024;
            const float* const ws = &sbuf[warp][s][0];
#pragma unroll
            for (int i = 0; i < 4; ++i) {
                const int row = i * 4 + u;
                const int cb  = (p * 4) ^ (i << 2) ^ ((i & 1) << 4);
                f32x4 v = *(const f32x4*)&ws[row * 64 + cb];
                *(f32x4*)&obase[i * 256 + lane * 4] = v;
            }
        }

        // ---- 5. rotate pipeline registers ----
#pragma unroll
        for (int s = 0; s < 2; ++s) {
            cC[s][0] = cL[s][0]; cC[s][1] = cL[s][1]; cC[s][2] = cL[s][2];
            nC[s][0] = nL[s][0]; nC[s][1] = nL[s][1]; nC[s][2] = nL[s][2];
            dC[s] = dN[s];  dN[s] = dL[s];  nbN[s] = nbL[s];
        }
    }
}

extern "C" void kernel_launch(void* const* d_in, const int* in_sizes, int n_in,
                              void* d_out, int out_size, void* d_ws, size_t ws_size,
                              hipStream_t stream) {
    const float* xyz  = (const float*)d_in[0];
    const float* dist = (const float*)d_in[1];
    const float* W1   = (const float*)d_in[2];
    const float* b1   = (const float*)d_in[3];
    const float* W2   = (const float*)d_in[4];
    const float* b2   = (const float*)d_in[5];
    const int*   idx  = (const int*)d_in[6];
    float* out = (float*)d_out;

    ppe_kernel<<<dim3(512), dim3(256), 0, stream>>>(xyz, dist, W1, b1, W2, b2, idx, out);
}

// Round 5
// 54.136 us; speedup vs baseline: 1.2845x; 1.2845x over previous
//
#include <hip/hip_runtime.h>
#include <hip/hip_bf16.h>

typedef __attribute__((ext_vector_type(8))) short bf16x8;
typedef __attribute__((ext_vector_type(4))) float f32x4;

__device__ __forceinline__ short f2bf(float x) {
    __hip_bfloat16 t = __float2bfloat16(x);
    return __builtin_bit_cast(short, t);
}

// B=16, N=4096, K=16, hidden=64, dim=64
// 65,536 groups of 16 rows (group = one point's 16 neighbors).
// grid: 768 blocks x 256 threads = 3072 waves, grid-stride (21-22 groups/wave).
//
// R5: both layers on MFMA with a hidden-unit permutation chosen so layer-1's
// swapped D-fragment (D1[hid][pt]) IS layer-2's B-fragment (no shuffle, no
// h transpose). Frees ~110 VGPRs (W1 hoard + h pipeline) -> 3 blocks/CU.
//   layer-1: A1 = folded W1 coeffs (8 ch: wa,wb,wd,bias), B1 = per-lane feat.
//   unit(32kt+8u+j) = 32kt + 16*(j>>2) + 4u + (j&3)  [bijective]
//   layer-2: A2[dim][k] = W2[unit(k)][dim], C-init = b2 -> D2[dim][pt].
// Output transpose via LDS: 4x ds_write_b128 / 4x ds_read_b128, XOR swizzle
// col ^ ((p&1)<<4) -> exactly 8 dwords/bank both sides (conflict-free).

__global__ __launch_bounds__(256, 3) void ppe_kernel(
    const float* __restrict__ xyz,   // [16,4096,3]
    const float* __restrict__ dist,  // [16,4096,16]
    const float* __restrict__ W1,    // [10,64]
    const float* __restrict__ b1,    // [64]
    const float* __restrict__ W2,    // [64,64]
    const float* __restrict__ b2,    // [64]
    const int*   __restrict__ idx,   // [16,4096,16] (int32)
    float* __restrict__ out)         // [16,4096,16,64]
{
    __shared__ float sbuf[4][1024];  // 4 KB per wave, wave-private

    const int lane = threadIdx.x & 63;
    const int warp = threadIdx.x >> 6;
    const int wid  = (blockIdx.x * blockDim.x + threadIdx.x) >> 6; // 0..3071
    const int u    = lane >> 4;   // 0..3
    const int p    = lane & 15;   // 0..15

    float* const ws = &sbuf[warp][0];

    // ---- persistent weight fragments ----
    // A1-frag (tile t): lane holds A1[16t+p][ch=8u+j]; only u==0 lanes nonzero.
    // channels: 0-2 wa=W1[c]+W1[6+c], 3-5 wb=W1[3+c]-W1[6+c], 6 wd=W1[9], 7 b1.
    bf16x8 w1f[4];
#pragma unroll
    for (int t = 0; t < 4; ++t) {
        const int hu = 16 * t + p;
#pragma unroll
        for (int j = 0; j < 8; ++j) {
            float coef;
            if (j < 3)      coef = W1[j * 64 + hu] + W1[(6 + j) * 64 + hu];
            else if (j < 6) coef = W1[j * 64 + hu] - W1[(j + 3) * 64 + hu];
            else if (j == 6) coef = W1[9 * 64 + hu];
            else             coef = b1[hu];
            w1f[t][j] = (u == 0) ? f2bf(coef) : (short)0;
        }
    }

    // A2-frag: lane holds A2[16dt+p][k=8u+j] = W2[unit(32kt+8u+j)][16dt+p]
    bf16x8 w2f[4][2];
#pragma unroll
    for (int dt = 0; dt < 4; ++dt)
#pragma unroll
        for (int kt = 0; kt < 2; ++kt)
#pragma unroll
            for (int j = 0; j < 8; ++j) {
                const int unit = 32 * kt + 16 * (j >> 2) + 4 * u + (j & 3);
                w2f[dt][kt][j] = f2bf(W2[unit * 64 + 16 * dt + p]);
            }

    // b2 as layer-2 C-init: D2 row = dim-in-tile = 4u+r
    float b2r[4][4];
#pragma unroll
    for (int dt = 0; dt < 4; ++dt)
#pragma unroll
        for (int r = 0; r < 4; ++r)
            b2r[dt][r] = b2[16 * dt + 4 * u + r];

    const short one_bf = f2bf(1.0f);
    const int NG = 65536, S = 3072;

    // ---- software-pipeline prologue (R3 structure) ----
    const int g0 = wid;
    const int row0 = g0 * 16 + p;
    int   nb0 = idx[row0];
    float dC  = dist[row0];
    const float* cp0 = xyz + (size_t)g0 * 3;
    float cC0 = cp0[0], cC1 = cp0[1], cC2 = cp0[2];
    const float* np0 = xyz + ((size_t)((g0 >> 12) * 4096) + nb0) * 3;
    float nC0 = np0[0], nC1 = np0[1], nC2 = np0[2];
    int g1 = g0 + S; if (g1 >= NG) g1 = g0;
    const int row1 = g1 * 16 + p;
    int   nbN = idx[row1];
    float dN  = dist[row1];

    for (int g = g0; g < NG; g += S) {
        int gB = g + S;     if (gB >= NG) gB = g;   // t+1 (clamped dummy)
        int gA = g + 2 * S; if (gA >= NG) gA = g;   // t+2 (clamped dummy)

        // ---- 1. issue xyz loads for t+1 (neighbor addr from resident nbN) ----
        const float* cpn = xyz + (size_t)gB * 3;
        float cL0 = cpn[0], cL1 = cpn[1], cL2 = cpn[2];
        const float* npn = xyz + ((size_t)((gB >> 12) * 4096) + nbN) * 3;
        float nL0 = npn[0], nL1 = npn[1], nL2 = npn[2];

        // ---- 2. issue idx/dist loads for t+2 ----
        const int rowA = gA * 16 + p;
        int   nbL = idx[rowA];
        float dL  = dist[rowA];

        // ---- 3. layer-1 MFMA: B1 = per-lane feat (u>=1 lanes ignored, A1=0) ----
        bf16x8 fa;
        fa[0] = f2bf(cC0); fa[1] = f2bf(cC1); fa[2] = f2bf(cC2);
        fa[3] = f2bf(nC0); fa[4] = f2bf(nC1); fa[5] = f2bf(nC2);
        fa[6] = f2bf(dC);  fa[7] = one_bf;

        f32x4 acc1[4];
#pragma unroll
        for (int t = 0; t < 4; ++t) {
            acc1[t] = (f32x4){0.f, 0.f, 0.f, 0.f};
            acc1[t] = __builtin_amdgcn_mfma_f32_16x16x32_bf16(w1f[t], fa, acc1[t], 0, 0, 0);
            // relu
            acc1[t][0] = fmaxf(acc1[t][0], 0.f);
            acc1[t][1] = fmaxf(acc1[t][1], 0.f);
            acc1[t][2] = fmaxf(acc1[t][2], 0.f);
            acc1[t][3] = fmaxf(acc1[t][3], 0.f);
        }

        // ---- 4. layer-2 B-frag directly from acc1 (permutation-matched) ----
        bf16x8 hb[2];
#pragma unroll
        for (int kt = 0; kt < 2; ++kt)
#pragma unroll
            for (int j = 0; j < 8; ++j)
                hb[kt][j] = f2bf(acc1[2 * kt + (j >> 2)][j & 3]);

        // ---- 5. layer-2 MFMA, bias in C-init: D2[dim][pt] ----
        f32x4 acc2[4];
#pragma unroll
        for (int dt = 0; dt < 4; ++dt) {
            acc2[dt] = (f32x4){b2r[dt][0], b2r[dt][1], b2r[dt][2], b2r[dt][3]};
            acc2[dt] = __builtin_amdgcn_mfma_f32_16x16x32_bf16(w2f[dt][0], hb[0], acc2[dt], 0, 0, 0);
            acc2[dt] = __builtin_amdgcn_mfma_f32_16x16x32_bf16(w2f[dt][1], hb[1], acc2[dt], 0, 0, 0);
        }

        // ---- 6. transpose via LDS: write D2[dim][pt] -> logical [pt][dim] ----
        // write at dword addr p*64 + ((16dt+4u) ^ ((p&1)<<4))  [conflict-free]
#pragma unroll
        for (int dt = 0; dt < 4; ++dt) {
            const int col = (16 * dt + 4 * u) ^ ((p & 1) << 4);
            *(f32x4*)&ws[p * 64 + col] = acc2[dt];
        }

        // ---- 7. LDS -> 4x 1KB contiguous NT dwordx4 ----
        // read row pt=4i+u, dwords (4p) ^ ((u&1)<<4)  [conflict-free]
        float* const obase = out + (size_t)g * 1024;
#pragma unroll
        for (int i = 0; i < 4; ++i) {
            const int pt = 4 * i + u;
            f32x4 v = *(const f32x4*)&ws[pt * 64 + ((4 * p) ^ ((u & 1) << 4))];
            __builtin_nontemporal_store(v, (f32x4*)&obase[i * 256 + lane * 4]);
        }

        // ---- 8. rotate pipeline registers ----
        cC0 = cL0; cC1 = cL1; cC2 = cL2;
        nC0 = nL0; nC1 = nL1; nC2 = nL2;
        dC  = dN;  dN  = dL;  nbN = nbL;
    }
}

extern "C" void kernel_launch(void* const* d_in, const int* in_sizes, int n_in,
                              void* d_out, int out_size, void* d_ws, size_t ws_size,
                              hipStream_t stream) {
    const float* xyz  = (const float*)d_in[0];
    const float* dist = (const float*)d_in[1];
    const float* W1   = (const float*)d_in[2];
    const float* b1   = (const float*)d_in[3];
    const float* W2   = (const float*)d_in[4];
    const float* b2   = (const float*)d_in[5];
    const int*   idx  = (const int*)d_in[6];
    float* out = (float*)d_out;

    ppe_kernel<<<dim3(768), dim3(256), 0, stream>>>(xyz, dist, W1, b1, W2, b2, idx, out);
}